// Round 3
// baseline (430.210 us; speedup 1.0000x reference)
//
#include <hip/hip_runtime.h>
#include <hip/hip_bf16.h>

typedef __attribute__((ext_vector_type(4))) float floatx4;
typedef __attribute__((ext_vector_type(2))) float floatx2;
typedef __attribute__((ext_vector_type(8))) __bf16 bf16x8;
typedef __attribute__((ext_vector_type(8))) unsigned short ushortx8;

__device__ __forceinline__ unsigned short f2bf(float x) {
    union { float f; unsigned u; } v; v.f = x;
    unsigned r = v.u + 0x7fffu + ((v.u >> 16) & 1u);
    return (unsigned short)(r >> 16);
}

__device__ __forceinline__ bf16x8 as_bf(ushortx8 v) {
    union { ushortx8 u; bf16x8 b; } x; x.u = v; return x.b;
}

__device__ __forceinline__ ushortx8 cvt8u(floatx4 lo, floatx4 hi) {
    union { ushortx8 v; __hip_bfloat162 h[4]; } u;
    float2 p;
    p.x = lo.x; p.y = lo.y; u.h[0] = __float22bfloat162_rn(p);
    p.x = lo.z; p.y = lo.w; u.h[1] = __float22bfloat162_rn(p);
    p.x = hi.x; p.y = hi.y; u.h[2] = __float22bfloat162_rn(p);
    p.x = hi.z; p.y = hi.w; u.h[3] = __float22bfloat162_rn(p);
    return u.v;
}

// ============ K1: U0 = Wf[:, :256]@OP, U1 = Wf[:, 256:]@OP,
//                  Vimg = Wv@W_img, Vtxt = Wv@W_text, + matvecs (c, vb_img, vb_txt)
__global__ void k1_tree(const float* __restrict__ W_fuse, const float* __restrict__ OP,
                        const float* __restrict__ ipw, const float* __restrict__ ipb,
                        const float* __restrict__ W_img, const float* __restrict__ W_text,
                        const float* __restrict__ opb, const float* __restrict__ b_img,
                        const float* __restrict__ b_text,
                        float* __restrict__ U0, float* __restrict__ U1,
                        float* __restrict__ Vimg, float* __restrict__ Vtxt,
                        float* __restrict__ vb_img, float* __restrict__ vb_txt,
                        float* __restrict__ cvec) {
    const int bid = blockIdx.x;
    const int t = threadIdx.x;
    const float* Wv = ipw + 512 * 256;
    if (bid == 96) {
        if (t < 256) {
            float a0 = opb[t], a1 = 0.f, a2 = 0.f;
            const float* oprow = OP + t * 256;
            const float* wvrow = Wv + t * 256;
            #pragma unroll 4
            for (int k = 0; k < 256; ++k) {
                a0 = fmaf(oprow[k], ipb[512 + k], a0);
                a1 = fmaf(wvrow[k], b_img[k], a1);
                a2 = fmaf(wvrow[k], b_text[k], a2);
            }
            cvec[t] = a0; vb_img[t] = a1; vb_txt[t] = a2;
        }
        return;
    }
    const float *A, *B; float* C; int lda, ldb, ldc, aoff, tm, tn;
    if (bid < 32) {
        int h = bid >> 4, tt = bid & 15;
        A = W_fuse; lda = 512; aoff = h * 256;
        B = OP; ldb = 256; C = h ? U1 : U0; ldc = 256;
        tm = tt >> 2; tn = tt & 3;
    } else {
        int b2 = bid - 32; int h = b2 >> 5; int tt = b2 & 31;
        A = Wv; lda = 256; aoff = 0;
        B = h ? W_text : W_img; ldb = 512; C = h ? Vtxt : Vimg; ldc = 512;
        tm = tt >> 3; tn = tt & 7;
    }
    __shared__ float As[16][68];
    __shared__ float Bs[16][68];
    const int arow = t >> 3, ak = (t & 7) * 2;
    const int brow = t >> 5, bc = (t & 31) * 2;
    const int ty = t >> 4, tx = t & 15;
    float acc[2][4] = {};
    for (int k0 = 0; k0 < 256; k0 += 16) {
        floatx2 av = *(const floatx2*)(A + (size_t)(tm * 64 + arow) * lda + aoff + k0 + ak);
        floatx2 bv = *(const floatx2*)(B + (size_t)(k0 + brow) * ldb + tn * 64 + bc);
        __syncthreads();
        As[ak + 0][arow] = av.x;
        As[ak + 1][arow] = av.y;
        *(floatx2*)&Bs[brow][bc] = bv;
        __syncthreads();
        #pragma unroll
        for (int kk = 0; kk < 16; ++kk) {
            floatx2 a = *(const floatx2*)&As[kk][ty * 2];
            floatx4 b = *(const floatx4*)&Bs[kk][tx * 4];
            acc[0][0] = fmaf(a.x, b.x, acc[0][0]); acc[0][1] = fmaf(a.x, b.y, acc[0][1]);
            acc[0][2] = fmaf(a.x, b.z, acc[0][2]); acc[0][3] = fmaf(a.x, b.w, acc[0][3]);
            acc[1][0] = fmaf(a.y, b.x, acc[1][0]); acc[1][1] = fmaf(a.y, b.y, acc[1][1]);
            acc[1][2] = fmaf(a.y, b.z, acc[1][2]); acc[1][3] = fmaf(a.y, b.w, acc[1][3]);
        }
    }
    #pragma unroll
    for (int i = 0; i < 2; ++i) {
        floatx4 o; o.x = acc[i][0]; o.y = acc[i][1]; o.z = acc[i][2]; o.w = acc[i][3];
        *(floatx4*)(C + (size_t)(tm * 64 + ty * 2 + i) * ldc + tn * 64 + tx * 4) = o;
    }
}

// ============ K2: A_half = U_h @ V_h -> Wt (bf16 B-fragment layout); bid 64: b_total
__global__ void k2_A(const float* __restrict__ U0, const float* __restrict__ U1,
                     const float* __restrict__ Vimg, const float* __restrict__ Vtxt,
                     const float* __restrict__ W_fuse, const float* __restrict__ b_fuse,
                     const float* __restrict__ vb_img, const float* __restrict__ vb_txt,
                     const float* __restrict__ cvec,
                     unsigned short* __restrict__ Wt, float* __restrict__ b_total) {
    const int bid = blockIdx.x;
    const int t = threadIdx.x;
    if (bid == 64) {
        if (t < 256) {
            float acc = b_fuse[t];
            const float* u0 = U0 + t * 256;
            const float* u1 = U1 + t * 256;
            const float* wf = W_fuse + t * 512;
            #pragma unroll 4
            for (int j = 0; j < 256; ++j) {
                acc = fmaf(u0[j], vb_img[j], acc);
                acc = fmaf(u1[j], vb_txt[j], acc);
                acc = fmaf(wf[j] + wf[j + 256], cvec[j], acc);
            }
            b_total[t] = acc;
        }
        return;
    }
    const int h = bid >> 5, tt = bid & 31;
    const float* A = h ? U1 : U0;
    const float* B = h ? Vtxt : Vimg;
    const int tm = tt >> 3, tn = tt & 7;
    __shared__ float As[16][68];
    __shared__ float Bs[16][68];
    const int arow = t >> 3, ak = (t & 7) * 2;
    const int brow = t >> 5, bc = (t & 31) * 2;
    const int n_l = t >> 3, oct = t & 7;
    float acc[8] = {};
    for (int k0 = 0; k0 < 256; k0 += 16) {
        floatx2 av = *(const floatx2*)(A + (size_t)(tm * 64 + arow) * 256 + k0 + ak);
        floatx2 bv = *(const floatx2*)(B + (size_t)(k0 + brow) * 512 + tn * 64 + bc);
        __syncthreads();
        As[ak + 0][arow] = av.x;
        As[ak + 1][arow] = av.y;
        *(floatx2*)&Bs[brow][bc] = bv;
        __syncthreads();
        #pragma unroll
        for (int kk = 0; kk < 16; ++kk) {
            float u = As[kk][n_l];
            floatx4 v0 = *(const floatx4*)&Bs[kk][oct * 8];
            floatx4 v1 = *(const floatx4*)&Bs[kk][oct * 8 + 4];
            acc[0] = fmaf(u, v0.x, acc[0]); acc[1] = fmaf(u, v0.y, acc[1]);
            acc[2] = fmaf(u, v0.z, acc[2]); acc[3] = fmaf(u, v0.w, acc[3]);
            acc[4] = fmaf(u, v1.x, acc[4]); acc[5] = fmaf(u, v1.y, acc[5]);
            acc[6] = fmaf(u, v1.z, acc[6]); acc[7] = fmaf(u, v1.w, acc[7]);
        }
    }
    const int n = tm * 64 + n_l;
    const int kg = h * 512 + tn * 64 + oct * 8;
    const int kq = kg >> 5, q = (kg >> 3) & 3;
    const int nt = n >> 4, nl = n & 15;
    union { ushortx8 v; unsigned short s[8]; } o;
    #pragma unroll
    for (int j = 0; j < 8; ++j) o.s[j] = f2bf(acc[j]);
    *(ushortx8*)&Wt[(size_t)((nt * 32 + kq) * 64 + q * 16 + nl) * 8] = o.v;
}

// ============ Main: 64 rows x 256 cols per block, K=1024, 8 K-stages of 128.
//   B (Wt, 512 KB, L2-resident) is streamed per block -> halving block count
//   (2048->1024) halves total B traffic; per-CU VMEM 5.1 MB -> 3 MB (the measured
//   bottleneck: r0/r1/r2 times scale with per-CU VMEM traffic, invariant to occupancy).
//   A staged f32->regs->bf16->LDS (33.8 KB dbuf), one barrier/stage, loads for
//   stage s+1 issued before compute(s). launch_bounds(256,3): VGPR cap ~170
//   (peak est ~145) -> NO spill (r2's 64-cap spilled: WRITE_SIZE 104 MB vs 65.5).
__global__ __launch_bounds__(256, 3)
void fused_gemm(const float* __restrict__ Ximg, const float* __restrict__ Xtxt,
                const unsigned short* __restrict__ Wt,
                const float* __restrict__ b_total, float* __restrict__ out) {
    // 2 buffers x 64 rows x 132 bf16 (264 B pitch: bank-start = (2*ml+4*q)%32
    // -> 4-way on ds_read_b128, ~1.6x floor; +pad keeps 16B alignment)
    __shared__ unsigned short lds[2][64 * 132];
    const int t = threadIdx.x, lane = t & 63, w = t >> 6;
    const int ml = lane & 15, q = lane >> 4;
    const size_t rowbase = (size_t)blockIdx.x * 64;
    // staging coords: thread owns row sr, f32 cols [sc, sc+32) of the 128-col strip
    const int sr = t >> 2;
    const int sc = (t & 3) * 32;

    floatx4 acc[4][4];
    #pragma unroll
    for (int mi = 0; mi < 4; ++mi)
        #pragma unroll
        for (int ni = 0; ni < 4; ++ni) acc[mi][ni] = (floatx4){0.f, 0.f, 0.f, 0.f};

    floatx4 lr[8];  // 32 f32 in flight during compute

    auto load_regs = [&](int s) {
        const float* X = (s < 4) ? Ximg : Xtxt;
        const float* gp = X + (rowbase + sr) * 512 + (s & 3) * 128 + sc;
        #pragma unroll
        for (int i = 0; i < 8; ++i) lr[i] = *(const floatx4*)(gp + i * 4);
    };
    auto write_stage = [&](int b) {
        unsigned short* lp = &lds[b][sr * 132 + sc];
        #pragma unroll
        for (int j = 0; j < 4; ++j)
            *(ushortx8*)(lp + j * 8) = cvt8u(lr[2 * j], lr[2 * j + 1]);
    };
    auto compute = [&](int s, int b) {
        #pragma unroll
        for (int kqi = 0; kqi < 4; ++kqi) {
            const int kq = s * 4 + kqi;
            bf16x8 af[4];
            #pragma unroll
            for (int mi = 0; mi < 4; ++mi) {
                const unsigned short* ap = &lds[b][(mi * 16 + ml) * 132 + kqi * 32 + q * 8];
                af[mi] = as_bf(*(const ushortx8*)ap);
            }
            #pragma unroll
            for (int ni = 0; ni < 4; ++ni) {
                ushortx8 bv = *(const ushortx8*)(Wt + (size_t)(((w * 4 + ni) * 32 + kq) * 64 + lane) * 8);
                #pragma unroll
                for (int mi = 0; mi < 4; ++mi)
                    acc[mi][ni] = __builtin_amdgcn_mfma_f32_16x16x32_bf16(af[mi], as_bf(bv), acc[mi][ni], 0, 0, 0);
            }
        }
    };

    load_regs(0);
    write_stage(0);
    __syncthreads();
    #pragma unroll 1
    for (int s = 0; s < 8; ++s) {
        if (s < 7) load_regs(s + 1);      // HBM latency hides under compute(s)
        compute(s, s & 1);
        if (s < 7) {
            write_stage((s + 1) & 1);
            __syncthreads();              // one barrier per stage
        }
    }

    // epilogue: C/D layout col=lane&15, row=q*4+e
    #pragma unroll
    for (int ni = 0; ni < 4; ++ni) {
        const int col = w * 64 + ni * 16 + ml;
        const float bias = b_total[col];
        #pragma unroll
        for (int mi = 0; mi < 4; ++mi) {
            const size_t r0 = rowbase + mi * 16 + q * 4;
            #pragma unroll
            for (int e = 0; e < 4; ++e) {
                float v = acc[mi][ni][e] + bias;
                out[(r0 + e) * 256 + col] = fmaxf(v, 0.f);
            }
        }
    }
}

extern "C" void kernel_launch(void* const* d_in, const int* in_sizes, int n_in,
                              void* d_out, int out_size, void* d_ws, size_t ws_size,
                              hipStream_t stream) {
    const float* text       = (const float*)d_in[0];
    const float* image      = (const float*)d_in[1];
    const float* W_text     = (const float*)d_in[2];
    const float* b_text     = (const float*)d_in[3];
    const float* W_img      = (const float*)d_in[4];
    const float* b_img      = (const float*)d_in[5];
    const float* in_proj_w  = (const float*)d_in[6];
    const float* in_proj_b  = (const float*)d_in[7];
    const float* out_proj_w = (const float*)d_in[8];
    const float* out_proj_b = (const float*)d_in[9];
    const float* W_fuse     = (const float*)d_in[10];
    const float* b_fuse     = (const float*)d_in[11];
    float* out = (float*)d_out;

    float* ws      = (float*)d_ws;
    float* U0      = ws;                 // 65536
    float* U1      = ws + 65536;         // 65536
    float* Vimg    = ws + 131072;        // 131072
    float* Vtxt    = ws + 262144;        // 131072
    float* vb_img  = ws + 393216;        // 256
    float* vb_txt  = ws + 393472;        // 256
    float* cvec    = ws + 393728;        // 256
    float* b_total = ws + 393984;        // 256
    unsigned short* Wt = (unsigned short*)(ws + 394240);  // 262144 bf16

    k1_tree<<<dim3(97), dim3(512), 0, stream>>>(W_fuse, out_proj_w, in_proj_w, in_proj_b,
                                                W_img, W_text, out_proj_b, b_img, b_text,
                                                U0, U1, Vimg, Vtxt, vb_img, vb_txt, cvec);
    k2_A<<<dim3(65), dim3(512), 0, stream>>>(U0, U1, Vimg, Vtxt, W_fuse, b_fuse,
                                             vb_img, vb_txt, cvec, Wt, b_total);
    fused_gemm<<<dim3(1024), dim3(256), 0, stream>>>(image, text, Wt, b_total, out);
}

// Round 4
// 390.926 us; speedup vs baseline: 1.1005x; 1.1005x over previous
//
#include <hip/hip_runtime.h>
#include <hip/hip_bf16.h>

typedef __attribute__((ext_vector_type(4))) float floatx4;
typedef __attribute__((ext_vector_type(2))) float floatx2;
typedef __attribute__((ext_vector_type(8))) __bf16 bf16x8;
typedef __attribute__((ext_vector_type(8))) unsigned short ushortx8;
typedef __attribute__((ext_vector_type(4))) unsigned short ushortx4;

__device__ __forceinline__ unsigned short f2bf(float x) {
    union { float f; unsigned u; } v; v.f = x;
    unsigned r = v.u + 0x7fffu + ((v.u >> 16) & 1u);
    return (unsigned short)(r >> 16);
}

__device__ __forceinline__ bf16x8 as_bf(ushortx8 v) {
    union { ushortx8 u; bf16x8 b; } x; x.u = v; return x.b;
}

__device__ __forceinline__ ushortx8 cvt8u(floatx4 lo, floatx4 hi) {
    union { ushortx8 v; __hip_bfloat162 h[4]; } u;
    float2 p;
    p.x = lo.x; p.y = lo.y; u.h[0] = __float22bfloat162_rn(p);
    p.x = lo.z; p.y = lo.w; u.h[1] = __float22bfloat162_rn(p);
    p.x = hi.x; p.y = hi.y; u.h[2] = __float22bfloat162_rn(p);
    p.x = hi.z; p.y = hi.w; u.h[3] = __float22bfloat162_rn(p);
    return u.v;
}

// ============ K1 (rewritten for occupancy): 32x32 tiles, 256 threads, 385 blocks.
//   bid 0..127   : U_h = Wf[:, h*256:+256] @ OP   (2 x 64 tiles)
//   bid 128..383 : V_x = Wv @ W_x                 (2 x 128 tiles)
//   bid 384      : matvecs (cvec, vb_img, vb_txt)
//   K=256 in 2 LDS chunks of 128; k-summation order identical to the old kernel
//   -> bit-identical results. Old version: 97 blocks of 512 thr = 0.4 blocks/CU,
//   ~130 us; this: 1.5 blocks/CU, ~4 barriers/block.
__global__ void k1_tree(const float* __restrict__ W_fuse, const float* __restrict__ OP,
                        const float* __restrict__ ipw, const float* __restrict__ ipb,
                        const float* __restrict__ W_img, const float* __restrict__ W_text,
                        const float* __restrict__ opb, const float* __restrict__ b_img,
                        const float* __restrict__ b_text,
                        float* __restrict__ U0, float* __restrict__ U1,
                        float* __restrict__ Vimg, float* __restrict__ Vtxt,
                        float* __restrict__ vb_img, float* __restrict__ vb_txt,
                        float* __restrict__ cvec) {
    const int bid = blockIdx.x;
    const int t = threadIdx.x;
    const float* Wv = ipw + 512 * 256;
    if (bid == 384) {
        float a0 = opb[t], a1 = 0.f, a2 = 0.f;
        const float* oprow = OP + t * 256;
        const float* wvrow = Wv + t * 256;
        #pragma unroll 4
        for (int k = 0; k < 256; ++k) {
            a0 = fmaf(oprow[k], ipb[512 + k], a0);
            a1 = fmaf(wvrow[k], b_img[k], a1);
            a2 = fmaf(wvrow[k], b_text[k], a2);
        }
        cvec[t] = a0; vb_img[t] = a1; vb_txt[t] = a2;
        return;
    }
    const float *A, *B; float* C; int lda, ldb, ldc, aoff, row0, col0;
    if (bid < 128) {
        int h = bid >> 6, tt = bid & 63;
        A = W_fuse; lda = 512; aoff = h * 256;
        B = OP; ldb = 256; C = h ? U1 : U0; ldc = 256;
        row0 = (tt >> 3) * 32; col0 = (tt & 7) * 32;
    } else {
        int b2 = bid - 128; int h = b2 >> 7; int tt = b2 & 127;
        A = Wv; lda = 256; aoff = 0;
        B = h ? W_text : W_img; ldb = 512; C = h ? Vtxt : Vimg; ldc = 512;
        row0 = (tt >> 4) * 32; col0 = (tt & 15) * 32;
    }
    __shared__ float As[32][132];   // 32 rows x 128 k (+4 pad, 16B-aligned rows)
    __shared__ float Bs[128][40];   // 128 k x 32 cols (+8 pad, 16B-aligned rows)
    const int ar = t >> 3, ac = (t & 7) * 16;   // A stage: row ar, 16 f32 from ac
    const int bk = t >> 1, bc = (t & 1) * 16;   // B stage: k-row bk, 16 f32 from bc
    const int r = t >> 3, c4 = (t & 7) * 4;     // compute: row r, cols [c4,c4+4)
    float acc0 = 0.f, acc1 = 0.f, acc2 = 0.f, acc3 = 0.f;
    for (int k0 = 0; k0 < 256; k0 += 128) {
        floatx4 at[4], bt[4];
        const float* ap = A + (size_t)(row0 + ar) * lda + aoff + k0 + ac;
        const float* bp = B + (size_t)(k0 + bk) * ldb + col0 + bc;
        #pragma unroll
        for (int i = 0; i < 4; ++i) at[i] = *(const floatx4*)(ap + i * 4);
        #pragma unroll
        for (int i = 0; i < 4; ++i) bt[i] = *(const floatx4*)(bp + i * 4);
        __syncthreads();
        #pragma unroll
        for (int i = 0; i < 4; ++i) *(floatx4*)&As[ar][ac + i * 4] = at[i];
        #pragma unroll
        for (int i = 0; i < 4; ++i) *(floatx4*)&Bs[bk][bc + i * 4] = bt[i];
        __syncthreads();
        #pragma unroll 4
        for (int k = 0; k < 128; ++k) {
            float a = As[r][k];
            floatx4 b = *(const floatx4*)&Bs[k][c4];
            acc0 = fmaf(a, b.x, acc0); acc1 = fmaf(a, b.y, acc1);
            acc2 = fmaf(a, b.z, acc2); acc3 = fmaf(a, b.w, acc3);
        }
    }
    floatx4 o; o.x = acc0; o.y = acc1; o.z = acc2; o.w = acc3;
    *(floatx4*)(C + (size_t)(row0 + r) * ldc + col0 + c4) = o;
}

// ============ K2 (rewritten): Wt_half = U_h @ V_h -> bf16 fragment layout.
//   bid 0..255: 32x32 tiles (2 halves x 8 n-tiles x 16 kg-tiles); bid 256: b_total.
__global__ void k2_A(const float* __restrict__ U0, const float* __restrict__ U1,
                     const float* __restrict__ Vimg, const float* __restrict__ Vtxt,
                     const float* __restrict__ W_fuse, const float* __restrict__ b_fuse,
                     const float* __restrict__ vb_img, const float* __restrict__ vb_txt,
                     const float* __restrict__ cvec,
                     unsigned short* __restrict__ Wt, float* __restrict__ b_total) {
    const int bid = blockIdx.x;
    const int t = threadIdx.x;
    if (bid == 256) {
        float acc = b_fuse[t];
        const float* u0 = U0 + t * 256;
        const float* u1 = U1 + t * 256;
        const float* wf = W_fuse + t * 512;
        #pragma unroll 4
        for (int j = 0; j < 256; ++j) {
            acc = fmaf(u0[j], vb_img[j], acc);
            acc = fmaf(u1[j], vb_txt[j], acc);
            acc = fmaf(wf[j] + wf[j + 256], cvec[j], acc);
        }
        b_total[t] = acc;
        return;
    }
    const int h = bid >> 7, tt = bid & 127;
    const float* A = h ? U1 : U0;   // [256 x 256], lda 256
    const float* B = h ? Vtxt : Vimg; // [256 x 512], ldb 512
    const int row0 = (tt >> 4) * 32, col0 = (tt & 15) * 32;
    __shared__ float As[32][132];
    __shared__ float Bs[128][40];
    const int ar = t >> 3, ac = (t & 7) * 16;
    const int bk = t >> 1, bc = (t & 1) * 16;
    const int r = t >> 3, c4 = (t & 7) * 4;
    float acc0 = 0.f, acc1 = 0.f, acc2 = 0.f, acc3 = 0.f;
    for (int k0 = 0; k0 < 256; k0 += 128) {
        floatx4 at[4], bt[4];
        const float* ap = A + (size_t)(row0 + ar) * 256 + k0 + ac;
        const float* bp = B + (size_t)(k0 + bk) * 512 + col0 + bc;
        #pragma unroll
        for (int i = 0; i < 4; ++i) at[i] = *(const floatx4*)(ap + i * 4);
        #pragma unroll
        for (int i = 0; i < 4; ++i) bt[i] = *(const floatx4*)(bp + i * 4);
        __syncthreads();
        #pragma unroll
        for (int i = 0; i < 4; ++i) *(floatx4*)&As[ar][ac + i * 4] = at[i];
        #pragma unroll
        for (int i = 0; i < 4; ++i) *(floatx4*)&Bs[bk][bc + i * 4] = bt[i];
        __syncthreads();
        #pragma unroll 4
        for (int k = 0; k < 128; ++k) {
            float a = As[r][k];
            floatx4 b = *(const floatx4*)&Bs[k][c4];
            acc0 = fmaf(a, b.x, acc0); acc1 = fmaf(a, b.y, acc1);
            acc2 = fmaf(a, b.z, acc2); acc3 = fmaf(a, b.w, acc3);
        }
    }
    // pack 4 consecutive kg into the bf16 B-fragment layout (same mapping as before)
    const int n = row0 + r;
    const int kgg = h * 512 + col0 + c4;
    const int kq = kgg >> 5, q = (kgg >> 3) & 3, e0 = kgg & 7;  // e0 in {0,4}
    const int nt = n >> 4, nl = n & 15;
    union { ushortx4 v; unsigned short s[4]; } o;
    o.s[0] = f2bf(acc0); o.s[1] = f2bf(acc1); o.s[2] = f2bf(acc2); o.s[3] = f2bf(acc3);
    *(ushortx4*)&Wt[(size_t)((nt * 32 + kq) * 64 + q * 16 + nl) * 8 + e0] = o.v;
}

// ============ Main: r2 structure (best measured: 140 us) — 32 rows x 256 cols,
//   bf16 LDS staging (33.8 KB dbuf), one barrier/stage, loads for s+1 issued
//   before compute(s). launch_bounds(256,3): VGPR cap 170 (needs ~105) -> kills
//   r2's spill (WRITE_SIZE was 104 MB vs 66 ideal) while LDS still allows 4 blk/CU.
__global__ __launch_bounds__(256, 3)
void fused_gemm(const float* __restrict__ Ximg, const float* __restrict__ Xtxt,
                const unsigned short* __restrict__ Wt,
                const float* __restrict__ b_total, float* __restrict__ out) {
    __shared__ unsigned short lds[2][32 * 264];
    const int t = threadIdx.x, lane = t & 63, w = t >> 6;
    const int ml = lane & 15, q = lane >> 4;
    const size_t rowbase = (size_t)blockIdx.x * 32;
    const int sr = t >> 3;
    const int sc = (t & 7) * 32;

    floatx4 acc[2][4];
    #pragma unroll
    for (int mi = 0; mi < 2; ++mi)
        #pragma unroll
        for (int ni = 0; ni < 4; ++ni) acc[mi][ni] = (floatx4){0.f, 0.f, 0.f, 0.f};

    floatx4 lr[8];  // 32 f32 in flight during compute

    auto load_regs = [&](int s) {
        const float* X = (s < 2) ? Ximg : Xtxt;
        const float* gp = X + (rowbase + sr) * 512 + (s & 1) * 256 + sc;
        #pragma unroll
        for (int i = 0; i < 8; ++i) lr[i] = *(const floatx4*)(gp + i * 4);
    };
    auto write_stage = [&](int b) {
        unsigned short* lp = &lds[b][sr * 264 + sc];
        #pragma unroll
        for (int j = 0; j < 4; ++j)
            *(ushortx8*)(lp + j * 8) = cvt8u(lr[2 * j], lr[2 * j + 1]);
    };
    auto compute = [&](int s, int b) {
        #pragma unroll
        for (int kqi = 0; kqi < 8; ++kqi) {
            const int kq = s * 8 + kqi;
            bf16x8 af[2];
            #pragma unroll
            for (int mi = 0; mi < 2; ++mi) {
                const unsigned short* ap = &lds[b][(mi * 16 + ml) * 264 + kqi * 32 + q * 8];
                af[mi] = as_bf(*(const ushortx8*)ap);
            }
            #pragma unroll
            for (int ni = 0; ni < 4; ++ni) {
                ushortx8 bv = *(const ushortx8*)(Wt + (size_t)(((w * 4 + ni) * 32 + kq) * 64 + lane) * 8);
                #pragma unroll
                for (int mi = 0; mi < 2; ++mi)
                    acc[mi][ni] = __builtin_amdgcn_mfma_f32_16x16x32_bf16(af[mi], as_bf(bv), acc[mi][ni], 0, 0, 0);
            }
        }
    };

    load_regs(0);
    write_stage(0);
    __syncthreads();
    #pragma unroll
    for (int s = 0; s < 4; ++s) {
        if (s < 3) load_regs(s + 1);
        compute(s, s & 1);
        if (s < 3) {
            write_stage((s + 1) & 1);
            __syncthreads();
        }
    }

    // epilogue: C/D layout col=lane&15, row=q*4+e
    #pragma unroll
    for (int ni = 0; ni < 4; ++ni) {
        const int col = w * 64 + ni * 16 + ml;
        const float bias = b_total[col];
        #pragma unroll
        for (int mi = 0; mi < 2; ++mi) {
            const size_t r0 = rowbase + mi * 16 + q * 4;
            #pragma unroll
            for (int e = 0; e < 4; ++e) {
                float v = acc[mi][ni][e] + bias;
                out[(r0 + e) * 256 + col] = fmaxf(v, 0.f);
            }
        }
    }
}

extern "C" void kernel_launch(void* const* d_in, const int* in_sizes, int n_in,
                              void* d_out, int out_size, void* d_ws, size_t ws_size,
                              hipStream_t stream) {
    const float* text       = (const float*)d_in[0];
    const float* image      = (const float*)d_in[1];
    const float* W_text     = (const float*)d_in[2];
    const float* b_text     = (const float*)d_in[3];
    const float* W_img      = (const float*)d_in[4];
    const float* b_img      = (const float*)d_in[5];
    const float* in_proj_w  = (const float*)d_in[6];
    const float* in_proj_b  = (const float*)d_in[7];
    const float* out_proj_w = (const float*)d_in[8];
    const float* out_proj_b = (const float*)d_in[9];
    const float* W_fuse     = (const float*)d_in[10];
    const float* b_fuse     = (const float*)d_in[11];
    float* out = (float*)d_out;

    float* ws      = (float*)d_ws;
    float* U0      = ws;                 // 65536
    float* U1      = ws + 65536;         // 65536
    float* Vimg    = ws + 131072;        // 131072
    float* Vtxt    = ws + 262144;        // 131072
    float* vb_img  = ws + 393216;        // 256
    float* vb_txt  = ws + 393472;        // 256
    float* cvec    = ws + 393728;        // 256
    float* b_total = ws + 393984;        // 256
    unsigned short* Wt = (unsigned short*)(ws + 394240);  // 262144 bf16

    k1_tree<<<dim3(385), dim3(256), 0, stream>>>(W_fuse, out_proj_w, in_proj_w, in_proj_b,
                                                 W_img, W_text, out_proj_b, b_img, b_text,
                                                 U0, U1, Vimg, Vtxt, vb_img, vb_txt, cvec);
    k2_A<<<dim3(257), dim3(256), 0, stream>>>(U0, U1, Vimg, Vtxt, W_fuse, b_fuse,
                                              vb_img, vb_txt, cvec, Wt, b_total);
    fused_gemm<<<dim3(2048), dim3(256), 0, stream>>>(image, text, Wt, b_total, out);
}